// Round 11
// baseline (1267.974 us; speedup 1.0000x reference)
//
#include <hip/hip_runtime.h>

using u16 = unsigned short;
typedef __attribute__((ext_vector_type(4))) float f32x4;
typedef __attribute__((ext_vector_type(8))) short bf16x8;
typedef unsigned short u16x8 __attribute__((ext_vector_type(8)));

static constexpr int S_TOK = 8192;   // B*T
static constexpr int NE    = 8;      // experts
static constexpr int CAP   = 1024;   // capacity = S/E
static constexpr int DDIM  = 2048;   // model dim
static constexpr int FDIM  = 8192;   // ffn dim

#define SCHED0() __builtin_amdgcn_sched_barrier(0)
#define S_VMCNT(n) do { asm volatile("s_waitcnt vmcnt(" #n ")" ::: "memory"); \
                        SCHED0(); } while (0)
#define LGKM0()    do { asm volatile("s_waitcnt lgkmcnt(0)" ::: "memory");    \
                        SCHED0(); } while (0)
#define S_BAR()                                  \
  do {                                           \
    SCHED0();                                    \
    __builtin_amdgcn_s_barrier();                \
    SCHED0();                                    \
  } while (0)

__device__ __forceinline__ u16 f2bf(float f) {
  union { float fv; unsigned uv; } v; v.fv = f;
  unsigned r = v.uv + 0x7fffu + ((v.uv >> 16) & 1u);
  return (u16)(r >> 16);
}

__device__ __forceinline__ unsigned cvt_pk_bf16(float lo, float hi) {
  unsigned r;
  asm("v_cvt_pk_bf16_f32 %0, %1, %2" : "=v"(r) : "v"(lo), "v"(hi));
  return r;  // RNE, identical to f2bf
}

__device__ __forceinline__ float gelu_tanh(float x) {
  float u = 0.7978845608028654f * (x + 0.044715f * x * x * x);
  float t = 1.0f - 2.0f / (__expf(2.0f * u) + 1.0f);
  return 0.5f * x * (1.0f + t);
}

__device__ __forceinline__ void gl_lds16(const void* g, void* l) {
  __builtin_amdgcn_global_load_lds(
      (const __attribute__((address_space(1))) unsigned int*)g,
      (__attribute__((address_space(3))) unsigned int*)l, 16, 0, 0);
}

// ---------------- fast zero fill ----------------
__global__ __launch_bounds__(256) void fill_zero_kernel(float4* __restrict__ p, int n4) {
  int i = blockIdx.x * 256 + threadIdx.x;
  int stride = gridDim.x * 256;
  float4 z = {0.f, 0.f, 0.f, 0.f};
  for (; i < n4; i += stride) p[i] = z;
}

// ---------------- gating: logits fp32, softmax, argmax ----------------
__global__ __launch_bounds__(256) void gating_kernel(
    const float* __restrict__ x, const float* __restrict__ wg,
    int* __restrict__ tok_expert, float* __restrict__ tok_gate) {
  int s = blockIdx.x * 4 + (threadIdx.x >> 6);
  int lane = threadIdx.x & 63;
  const float4* xv = (const float4*)(x + (size_t)s * DDIM + lane * 32);
  float acc[8];
#pragma unroll
  for (int e = 0; e < 8; ++e) acc[e] = 0.f;
#pragma unroll
  for (int j = 0; j < 8; ++j) {
    float4 xx = xv[j];
#pragma unroll
    for (int c = 0; c < 4; ++c) {
      int i = lane * 32 + j * 4 + c;
      const float4* wrow = (const float4*)(wg + (size_t)i * 8);
      float4 w0 = wrow[0], w1 = wrow[1];
      float xe = (c == 0) ? xx.x : (c == 1) ? xx.y : (c == 2) ? xx.z : xx.w;
      acc[0] += xe * w0.x; acc[1] += xe * w0.y; acc[2] += xe * w0.z; acc[3] += xe * w0.w;
      acc[4] += xe * w1.x; acc[5] += xe * w1.y; acc[6] += xe * w1.z; acc[7] += xe * w1.w;
    }
  }
#pragma unroll
  for (int off = 32; off > 0; off >>= 1)
#pragma unroll
    for (int e = 0; e < 8; ++e) acc[e] += __shfl_xor(acc[e], off, 64);
  if (lane == 0) {
    float m = acc[0]; int ai = 0;
#pragma unroll
    for (int e = 1; e < 8; ++e) if (acc[e] > m) { m = acc[e]; ai = e; }
    float sum = 0.f;
#pragma unroll
    for (int e = 0; e < 8; ++e) sum += expf(acc[e] - m);
    tok_expert[s] = ai;
    tok_gate[s] = 1.0f / sum;
  }
}

__global__ void init_slots(int* tok_of_slot, float* gate_of_slot) {
  int i = blockIdx.x * 256 + threadIdx.x;
  tok_of_slot[i] = -1;
  gate_of_slot[i] = 0.f;
}

// -------- deterministic capacity assignment (cumsum over token order) --------
__global__ __launch_bounds__(1024) void scan_kernel(
    const int* __restrict__ tok_expert, const float* __restrict__ tok_gate,
    int* __restrict__ tok_of_slot, float* __restrict__ gate_of_slot) {
  __shared__ int cnt[1024][8];
  int t = threadIdx.x;
  int e8[8];
  int local[8];
#pragma unroll
  for (int e = 0; e < 8; ++e) local[e] = 0;
#pragma unroll
  for (int j = 0; j < 8; ++j) {
    int e = tok_expert[t * 8 + j];
    e8[j] = e;
    local[e]++;
  }
#pragma unroll
  for (int e = 0; e < 8; ++e) cnt[t][e] = local[e];
  __syncthreads();
  for (int off = 1; off < 1024; off <<= 1) {
    int v[8];
    bool has = (t >= off);
    if (has) {
#pragma unroll
      for (int e = 0; e < 8; ++e) v[e] = cnt[t - off][e];
    }
    __syncthreads();
    if (has) {
#pragma unroll
      for (int e = 0; e < 8; ++e) cnt[t][e] += v[e];
    }
    __syncthreads();
  }
  int base[8];
#pragma unroll
  for (int e = 0; e < 8; ++e) base[e] = (t == 0) ? 0 : cnt[t - 1][e];
#pragma unroll
  for (int j = 0; j < 8; ++j) {
    int s = t * 8 + j;
    int e = e8[j];
    int p = base[e]++;
    if (p < CAP) {
      tok_of_slot[e * CAP + p] = s;
      gate_of_slot[e * CAP + p] = tok_gate[s];
    }
  }
}

// ---- dispatch: gather x rows -> bf16 Xd [E][CAP][D]; empty slots -> zeros ----
__global__ __launch_bounds__(256) void scatter_kernel(
    const int* __restrict__ tok_of_slot, const float* __restrict__ x,
    u16* __restrict__ Xd) {
  int slot = blockIdx.x;
  int s = tok_of_slot[slot];
  int t = threadIdx.x;
  u16x8 v;
  if (s >= 0) {
    const float4* xr = (const float4*)(x + (size_t)s * DDIM + t * 8);
    float4 a = xr[0], b = xr[1];
    v[0] = f2bf(a.x); v[1] = f2bf(a.y); v[2] = f2bf(a.z); v[3] = f2bf(a.w);
    v[4] = f2bf(b.x); v[5] = f2bf(b.y); v[6] = f2bf(b.z); v[7] = f2bf(b.w);
  } else {
#pragma unroll
    for (int j = 0; j < 8; ++j) v[j] = 0;
  }
  *(u16x8*)(Xd + (size_t)slot * DDIM + t * 8) = v;
}

// ---- deep-pipelined bf16 GEMM, fused fp32->bf16 weight staging ----
// C[1024xN] = A[1024xK](bf16) * W[KxN](fp32, row-major).
// BM=BN=256, BK=64, 512 thr / 8 waves (2M x 4N), wave-tile 128x64.
// LDS 160 KB: A-ring of 3 slots (32 KB each) + B double-buffer (2 x 32 KB).
// Pipeline depth 2: during tile kt, issue B(kt+2)->regs (sets bvE/bvO by kt
// parity) then A(kt+2)->slot (kt+2)%3. Drain is counted: vmcnt(12) retires
// exactly {B(kt+1), A(kt+1)} (both issued a FULL tile earlier -> latency
// hidden) and leaves {B(kt+2), A(kt+2)} in flight ACROSS the barrier.
// Same F(row)=(row^(row>>2))&7 chunk swizzle as R9 (reads AND B-writes
// conflict-free; B global loads wave-contiguous 1024B).
// EPI=0: gelu -> bf16 H ; EPI=1: gated scatter to fp32 out.
template <int KDIM, int NDIM, int EPI, int NEXP>
__global__ __launch_bounds__(512, 1) void moe_gemm(
    const u16* __restrict__ A, const float* __restrict__ Bf,
    u16* __restrict__ Hout, float* __restrict__ Fout,
    const int* __restrict__ tok_of_slot, const float* __restrict__ gate_of_slot,
    int e_base) {
  constexpr int MDIM = 1024;
  constexpr int BM = 256, BN = 256, BK = 64;
  constexpr int MT = MDIM / BM;              // 4
  constexpr int NK = KDIM / BK;              // >= 32, even
  constexpr int ASZ = BM * BK;               // 16384 u16 (32 KB)
  constexpr int BSZ = BN * BK;               // 16384 u16 (32 KB)
  __shared__ u16 lds[3 * ASZ + 2 * BSZ];     // 160 KB exactly

  u16* const Ab = lds;
  u16* const Bb = lds + 3 * ASZ;

  const int t = threadIdx.x;
  const int lane = t & 63, wave = t >> 6;
  const int wr = wave >> 2, wc = wave & 3;   // 2 x 4

  int id = blockIdx.x;
  int ez = id & (NEXP - 1);
  int w = id / NEXP;
  int mt = w & (MT - 1);
  int nt = w / MT;
  int m0 = mt * BM, n0 = nt * BN;
  int e = e_base + ez;

  const u16* Ae = A + (size_t)ez * MDIM * KDIM;
  const float* Be = Bf + (size_t)ez * (size_t)KDIM * NDIM;

  // A staging (global_load_lds, source pre-swizzled by F(row))
  const u16* aSrc[4];
  int ldsOffA[4];
#pragma unroll
  for (int p = 0; p < 4; ++p) {
    int c = t + p * 512;
    int row = c >> 3;
    int fr = (row ^ (row >> 2)) & 7;
    int j = (c & 7) ^ fr;
    aSrc[p] = Ae + (size_t)(m0 + row) * KDIM + j * 8;
    ldsOffA[p] = c * 8;
  }

  // B reg staging: bq = lane-contiguous n, boct = wave's k-oct
  const int bq = (t & 63) * 4;     // n base; wave covers 1024B contiguous
  const int boct = t >> 6;         // logical k-chunk 0..7 (= wave id)
  const float* bP = Be + (size_t)(boct * 8) * NDIM + n0 + bq;
  int bWOff[4];
#pragma unroll
  for (int c = 0; c < 4; ++c) {
    int row = bq + c;
    int fr = (row ^ (row >> 2)) & 7;
    bWOff[c] = row * 64 + (boct ^ fr) * 8;  // u16 units within B buf
  }

  // ds_read addressing: col = (K ^ 4*((kk^frag)&1)) * 8, K = h ^ (r&7) ^ (r>>2)
  const int r = lane & 15, h = lane >> 4;
  const int Kk = h ^ (r & 7) ^ (r >> 2);
  const int pE = Kk * 8;            // (kk ^ frag) even
  const int pO = (Kk ^ 4) * 8;      // (kk ^ frag) odd
  const int aBase = (wr * 128 + r) * 64;   // A row base within slot
  const int bBase = (wc * 64 + r) * 64;    // B row base within buf

  f32x4 acc[8][4];
#pragma unroll
  for (int m = 0; m < 8; ++m)
#pragma unroll
    for (int n = 0; n < 4; ++n) acc[m][n] = f32x4{0.f, 0.f, 0.f, 0.f};

  f32x4 bvE[8], bvO[8];

  // ---- prologue: B(0)->bvE, A(0)->slot0, B(1)->bvO, A(1)->slot1 ----
#pragma unroll
  for (int j = 0; j < 8; ++j) bvE[j] = *(const f32x4*)(bP + (size_t)j * NDIM);
  SCHED0();
#pragma unroll
  for (int p = 0; p < 4; ++p) gl_lds16(aSrc[p], Ab + ldsOffA[p]);
  SCHED0();
#pragma unroll
  for (int j = 0; j < 8; ++j) bvO[j] = *(const f32x4*)(bP + (size_t)(BK + j) * NDIM);
  SCHED0();
#pragma unroll
  for (int p = 0; p < 4; ++p) gl_lds16(aSrc[p] + BK, Ab + ASZ + ldsOffA[p]);
  SCHED0();
  S_VMCNT(16);   // retire B(0)
#pragma unroll
  for (int c = 0; c < 4; ++c) {
    union { u16x8 v; unsigned w[4]; } o;
#pragma unroll
    for (int j = 0; j < 4; ++j) o.w[j] = cvt_pk_bf16(bvE[2 * j][c], bvE[2 * j + 1][c]);
    *(u16x8*)(Bb + bWOff[c]) = o.v;
  }
  S_VMCNT(12);   // retire A(0); leaves B(1)[8]+A(1)[4] in flight
  LGKM0();
  S_BAR();

  int aC = 0;    // current A slot
  for (int kt = 0; kt < NK; ++kt) {
    const u16* sa = Ab + aC * ASZ;
    const u16* sbB = Bb + (kt & 1) * BSZ;
    u16* nbB = Bb + ((kt + 1) & 1) * BSZ;
    int a2 = aC + 2; if (a2 >= 3) a2 -= 3;
    const bool pre2 = (kt + 2 < NK);
    const bool pre1 = (kt + 1 < NK);

    if (pre2) {
      const int ko = (kt + 2) * BK;
      if ((kt & 1) == 0) {
#pragma unroll
        for (int j = 0; j < 8; ++j) bvE[j] = *(const f32x4*)(bP + (size_t)(ko + j) * NDIM);
      } else {
#pragma unroll
        for (int j = 0; j < 8; ++j) bvO[j] = *(const f32x4*)(bP + (size_t)(ko + j) * NDIM);
      }
      SCHED0();
#pragma unroll
      for (int p = 0; p < 4; ++p) gl_lds16(aSrc[p] + ko, Ab + a2 * ASZ + ldsOffA[p]);
      SCHED0();
    }

#pragma unroll
    for (int kk = 0; kk < 2; ++kk) {
      bf16x8 af[8], bv[4];
#pragma unroll
      for (int m = 0; m < 8; ++m)
        af[m] = *(const bf16x8*)(sa + aBase + m * 1024 + (((kk ^ m) & 1) ? pO : pE));
#pragma unroll
      for (int n = 0; n < 4; ++n)
        bv[n] = *(const bf16x8*)(sbB + bBase + n * 1024 + (((kk ^ n) & 1) ? pO : pE));
      __builtin_amdgcn_s_setprio(1);
#pragma unroll
      for (int m = 0; m < 8; ++m)
#pragma unroll
        for (int n = 0; n < 4; ++n)
          acc[m][n] = __builtin_amdgcn_mfma_f32_16x16x32_bf16(af[m], bv[n], acc[m][n], 0, 0, 0);
      __builtin_amdgcn_s_setprio(0);
    }

    if (pre1) {
      if (pre2) { S_VMCNT(12); }   // retire B(kt+1)+A(kt+1); keep kt+2 in flight
      else      { S_VMCNT(0); }    // tail
      if ((kt & 1) == 0) {
#pragma unroll
        for (int c = 0; c < 4; ++c) {
          union { u16x8 v; unsigned w[4]; } o;
#pragma unroll
          for (int j = 0; j < 4; ++j) o.w[j] = cvt_pk_bf16(bvO[2 * j][c], bvO[2 * j + 1][c]);
          *(u16x8*)(nbB + bWOff[c]) = o.v;
        }
      } else {
#pragma unroll
        for (int c = 0; c < 4; ++c) {
          union { u16x8 v; unsigned w[4]; } o;
#pragma unroll
          for (int j = 0; j < 4; ++j) o.w[j] = cvt_pk_bf16(bvE[2 * j][c], bvE[2 * j + 1][c]);
          *(u16x8*)(nbB + bWOff[c]) = o.v;
        }
      }
      LGKM0();
    }
    S_BAR();
    aC = (aC + 1 == 3) ? 0 : aC + 1;
  }

  // ---------- epilogue ----------
  if (EPI == 0) {
    u16* Hrow = Hout + (size_t)ez * MDIM * NDIM;
#pragma unroll
    for (int m = 0; m < 8; ++m) {
#pragma unroll
      for (int rr = 0; rr < 4; ++rr) {
        int row = m0 + wr * 128 + m * 16 + h * 4 + rr;
#pragma unroll
        for (int n = 0; n < 4; ++n) {
          int col = n0 + wc * 64 + n * 16 + r;
          Hrow[(size_t)row * NDIM + col] = f2bf(gelu_tanh(acc[m][n][rr]));
        }
      }
    }
  } else {
#pragma unroll
    for (int m = 0; m < 8; ++m) {
#pragma unroll
      for (int rr = 0; rr < 4; ++rr) {
        int slot_in_e = m0 + wr * 128 + m * 16 + h * 4 + rr;
        int gslot = e * CAP + slot_in_e;
        int s = tok_of_slot[gslot];
        if (s >= 0) {
          float g = gate_of_slot[gslot];
#pragma unroll
          for (int n = 0; n < 4; ++n) {
            int col = n0 + wc * 64 + n * 16 + r;
            Fout[(size_t)s * NDIM + col] = g * acc[m][n][rr];
          }
        }
      }
    }
  }
}

extern "C" void kernel_launch(void* const* d_in, const int* in_sizes, int n_in,
                              void* d_out, int out_size, void* d_ws, size_t ws_size,
                              hipStream_t stream) {
  (void)in_sizes; (void)n_in;
  const float* x  = (const float*)d_in[0];
  const float* wg = (const float*)d_in[1];
  const float* w1 = (const float*)d_in[2];
  const float* w2 = (const float*)d_in[3];
  float* out = (float*)d_out;

  char* ws = (char*)d_ws;
  size_t off = 0;
  auto alloc = [&](size_t b) {
    off = (off + 255) & ~(size_t)255;
    char* p = ws + off;
    off += b;
    return p;
  };
  int*   tok_expert   = (int*)alloc((size_t)S_TOK * 4);
  float* tok_gate     = (float*)alloc((size_t)S_TOK * 4);
  int*   tok_of_slot  = (int*)alloc((size_t)NE * CAP * 4);
  float* gate_of_slot = (float*)alloc((size_t)NE * CAP * 4);
  u16*   Xd           = (u16*)alloc((size_t)NE * CAP * DDIM * 2);
  size_t off_common = off;

  const size_t H_big = (size_t)NE * CAP * FDIM * 2;   // 134 MB
  const size_t H_sm  = (size_t)CAP * FDIM * 2;        // 16.8 MB
  bool big = ws_size >= off_common + H_big + 1024;

  fill_zero_kernel<<<2048, 256, 0, stream>>>((float4*)out, out_size / 4);
  gating_kernel<<<S_TOK / 4, 256, 0, stream>>>(x, wg, tok_expert, tok_gate);
  init_slots<<<(NE * CAP) / 256, 256, 0, stream>>>(tok_of_slot, gate_of_slot);
  scan_kernel<<<1, 1024, 0, stream>>>(tok_expert, tok_gate, tok_of_slot, gate_of_slot);
  scatter_kernel<<<NE * CAP, 256, 0, stream>>>(tok_of_slot, x, Xd);

  if (big) {
    u16* H = (u16*)alloc(H_big);
    moe_gemm<DDIM, FDIM, 0, NE><<<dim3(NE * 4 * (FDIM / 256)), 512, 0, stream>>>(
        Xd, w1, H, nullptr, tok_of_slot, gate_of_slot, 0);
    moe_gemm<FDIM, DDIM, 1, NE><<<dim3(NE * 4 * (DDIM / 256)), 512, 0, stream>>>(
        H, w2, nullptr, out, tok_of_slot, gate_of_slot, 0);
  } else {
    u16* H = (u16*)alloc(H_sm);
    for (int e = 0; e < NE; ++e) {
      moe_gemm<DDIM, FDIM, 0, 1><<<dim3(4 * (FDIM / 256)), 512, 0, stream>>>(
          Xd + (size_t)e * CAP * DDIM, w1 + (size_t)e * DDIM * FDIM, H, nullptr,
          tok_of_slot, gate_of_slot, e);
      moe_gemm<FDIM, DDIM, 1, 1><<<dim3(4 * (DDIM / 256)), 512, 0, stream>>>(
          H, w2 + (size_t)e * FDIM * DDIM, nullptr, out,
          tok_of_slot, gate_of_slot, e);
    }
  }
}

// Round 12
// 770.719 us; speedup vs baseline: 1.6452x; 1.6452x over previous
//
#include <hip/hip_runtime.h>

using u16 = unsigned short;
typedef __attribute__((ext_vector_type(4))) float f32x4;
typedef __attribute__((ext_vector_type(16))) float f32x16;
typedef __attribute__((ext_vector_type(8))) short bf16x8;
typedef unsigned short u16x8 __attribute__((ext_vector_type(8)));

static constexpr int S_TOK = 8192;   // B*T
static constexpr int NE    = 8;      // experts
static constexpr int CAP   = 1024;   // capacity = S/E
static constexpr int DDIM  = 2048;   // model dim
static constexpr int FDIM  = 8192;   // ffn dim

#define S_WAIT_ALL() asm volatile("s_waitcnt vmcnt(0) lgkmcnt(0)" ::: "memory")
#define S_BAR()                                  \
  do {                                           \
    __builtin_amdgcn_sched_barrier(0);           \
    __builtin_amdgcn_s_barrier();                \
    __builtin_amdgcn_sched_barrier(0);           \
  } while (0)

__device__ __forceinline__ u16 f2bf(float f) {
  union { float fv; unsigned uv; } v; v.fv = f;
  unsigned r = v.uv + 0x7fffu + ((v.uv >> 16) & 1u);
  return (u16)(r >> 16);
}

__device__ __forceinline__ unsigned cvt_pk_bf16(float lo, float hi) {
  unsigned r;
  asm("v_cvt_pk_bf16_f32 %0, %1, %2" : "=v"(r) : "v"(lo), "v"(hi));
  return r;  // RNE, identical to f2bf
}

__device__ __forceinline__ float gelu_tanh(float x) {
  float u = 0.7978845608028654f * (x + 0.044715f * x * x * x);
  float t = 1.0f - 2.0f / (__expf(2.0f * u) + 1.0f);
  return 0.5f * x * (1.0f + t);
}

__device__ __forceinline__ void gl_lds16(const void* g, void* l) {
  __builtin_amdgcn_global_load_lds(
      (const __attribute__((address_space(1))) unsigned int*)g,
      (__attribute__((address_space(3))) unsigned int*)l, 16, 0, 0);
}

// ---------------- fast zero fill ----------------
__global__ __launch_bounds__(256) void fill_zero_kernel(float4* __restrict__ p, int n4) {
  int i = blockIdx.x * 256 + threadIdx.x;
  int stride = gridDim.x * 256;
  float4 z = {0.f, 0.f, 0.f, 0.f};
  for (; i < n4; i += stride) p[i] = z;
}

// ---------------- gating: logits fp32, softmax, argmax ----------------
__global__ __launch_bounds__(256) void gating_kernel(
    const float* __restrict__ x, const float* __restrict__ wg,
    int* __restrict__ tok_expert, float* __restrict__ tok_gate) {
  int s = blockIdx.x * 4 + (threadIdx.x >> 6);
  int lane = threadIdx.x & 63;
  const float4* xv = (const float4*)(x + (size_t)s * DDIM + lane * 32);
  float acc[8];
#pragma unroll
  for (int e = 0; e < 8; ++e) acc[e] = 0.f;
#pragma unroll
  for (int j = 0; j < 8; ++j) {
    float4 xx = xv[j];
#pragma unroll
    for (int c = 0; c < 4; ++c) {
      int i = lane * 32 + j * 4 + c;
      const float4* wrow = (const float4*)(wg + (size_t)i * 8);
      float4 w0 = wrow[0], w1 = wrow[1];
      float xe = (c == 0) ? xx.x : (c == 1) ? xx.y : (c == 2) ? xx.z : xx.w;
      acc[0] += xe * w0.x; acc[1] += xe * w0.y; acc[2] += xe * w0.z; acc[3] += xe * w0.w;
      acc[4] += xe * w1.x; acc[5] += xe * w1.y; acc[6] += xe * w1.z; acc[7] += xe * w1.w;
    }
  }
#pragma unroll
  for (int off = 32; off > 0; off >>= 1)
#pragma unroll
    for (int e = 0; e < 8; ++e) acc[e] += __shfl_xor(acc[e], off, 64);
  if (lane == 0) {
    float m = acc[0]; int ai = 0;
#pragma unroll
    for (int e = 1; e < 8; ++e) if (acc[e] > m) { m = acc[e]; ai = e; }
    float sum = 0.f;
#pragma unroll
    for (int e = 0; e < 8; ++e) sum += expf(acc[e] - m);
    tok_expert[s] = ai;
    tok_gate[s] = 1.0f / sum;
  }
}

__global__ void init_slots(int* tok_of_slot, float* gate_of_slot) {
  int i = blockIdx.x * 256 + threadIdx.x;
  tok_of_slot[i] = -1;
  gate_of_slot[i] = 0.f;
}

// -------- deterministic capacity assignment (cumsum over token order) --------
__global__ __launch_bounds__(1024) void scan_kernel(
    const int* __restrict__ tok_expert, const float* __restrict__ tok_gate,
    int* __restrict__ tok_of_slot, float* __restrict__ gate_of_slot) {
  __shared__ int cnt[1024][8];
  int t = threadIdx.x;
  int e8[8];
  int local[8];
#pragma unroll
  for (int e = 0; e < 8; ++e) local[e] = 0;
#pragma unroll
  for (int j = 0; j < 8; ++j) {
    int e = tok_expert[t * 8 + j];
    e8[j] = e;
    local[e]++;
  }
#pragma unroll
  for (int e = 0; e < 8; ++e) cnt[t][e] = local[e];
  __syncthreads();
  for (int off = 1; off < 1024; off <<= 1) {
    int v[8];
    bool has = (t >= off);
    if (has) {
#pragma unroll
      for (int e = 0; e < 8; ++e) v[e] = cnt[t - off][e];
    }
    __syncthreads();
    if (has) {
#pragma unroll
      for (int e = 0; e < 8; ++e) cnt[t][e] += v[e];
    }
    __syncthreads();
  }
  int base[8];
#pragma unroll
  for (int e = 0; e < 8; ++e) base[e] = (t == 0) ? 0 : cnt[t - 1][e];
#pragma unroll
  for (int j = 0; j < 8; ++j) {
    int s = t * 8 + j;
    int e = e8[j];
    int p = base[e]++;
    if (p < CAP) {
      tok_of_slot[e * CAP + p] = s;
      gate_of_slot[e * CAP + p] = tok_gate[s];
    }
  }
}

// ---- dispatch: gather x rows -> bf16 Xd [E][CAP][D]; empty slots -> zeros ----
__global__ __launch_bounds__(256) void scatter_kernel(
    const int* __restrict__ tok_of_slot, const float* __restrict__ x,
    u16* __restrict__ Xd) {
  int slot = blockIdx.x;
  int s = tok_of_slot[slot];
  int t = threadIdx.x;
  u16x8 v;
  if (s >= 0) {
    const float4* xr = (const float4*)(x + (size_t)s * DDIM + t * 8);
    float4 a = xr[0], b = xr[1];
    v[0] = f2bf(a.x); v[1] = f2bf(a.y); v[2] = f2bf(a.z); v[3] = f2bf(a.w);
    v[4] = f2bf(b.x); v[5] = f2bf(b.y); v[6] = f2bf(b.z); v[7] = f2bf(b.w);
  } else {
#pragma unroll
    for (int j = 0; j < 8; ++j) v[j] = 0;
  }
  *(u16x8*)(Xd + (size_t)slot * DDIM + t * 8) = v;
}

// ---- pipelined bf16 GEMM (R9 schedule) with 32x32x16 MFMA ----
// C[1024xN] = A[1024xK](bf16) * W[KxN](fp32, row-major).
// BM=BN=256, BK=64, 512 thr / 8 waves (2M x 4N), wave-tile 128x64 as
// 4m x 2n tiles of 32x32. Per K-tile: 4 MFMA-steps (K=16 each); per step
// each lane reads A rows (lane&31) k-half (lane>>5) via b128.
// Swizzle F(row)=(row^(row>>2))&7 (row-dependence folds to lane&31 only):
// reads and B ds_writes both bank-conflict-free; B global loads contiguous.
// B reg-loads issued BEFORE A gl_lds so the cvt's implicit wait is vmcnt(4),
// not a full drain. One vmcnt(0)+lgkmcnt(0)+barrier per K-tile.
// C/D layout (m74/m101): col=lane&31, row=(reg&3)+8*(reg>>2)+4*(lane>>5).
// EPI=0: gelu -> bf16 H ; EPI=1: gated scatter to fp32 out.
template <int KDIM, int NDIM, int EPI, int NEXP>
__global__ __launch_bounds__(512, 2) void moe_gemm(
    const u16* __restrict__ A, const float* __restrict__ Bf,
    u16* __restrict__ Hout, float* __restrict__ Fout,
    const int* __restrict__ tok_of_slot, const float* __restrict__ gate_of_slot,
    int e_base) {
  constexpr int MDIM = 1024;
  constexpr int BM = 256, BN = 256, BK = 64;
  constexpr int MT = MDIM / BM;              // 4
  constexpr int NK = KDIM / BK;
  constexpr int ASZ = BM * BK;               // 16384 u16 (32 KB)
  constexpr int BSZ = BN * BK;               // 16384 u16 (32 KB)
  constexpr int BUFSZ = ASZ + BSZ;
  __shared__ u16 lds[2 * BUFSZ];             // 128 KB

  const int t = threadIdx.x;
  const int lane = t & 63, wave = t >> 6;
  const int wr = wave >> 2, wc = wave & 3;   // 2 x 4

  int id = blockIdx.x;
  int ez = id & (NEXP - 1);
  int w = id / NEXP;
  int mt = w & (MT - 1);
  int nt = w / MT;
  int m0 = mt * BM, n0 = nt * BN;
  int e = e_base + ez;

  const u16* Ae = A + (size_t)ez * MDIM * KDIM;
  const float* Be = Bf + (size_t)ez * (size_t)KDIM * NDIM;

  // A staging (global_load_lds, source pre-swizzled by F(row))
  const u16* aSrc[4];
  int ldsOffA[4];
#pragma unroll
  for (int p = 0; p < 4; ++p) {
    int c = t + p * 512;
    int row = c >> 3;
    int fr = (row ^ (row >> 2)) & 7;
    int j = (c & 7) ^ fr;
    aSrc[p] = Ae + (size_t)(m0 + row) * KDIM + j * 8;
    ldsOffA[p] = c * 8;
  }

  // B reg staging: bq = lane-contiguous n, boct = wave's k-oct
  const int bq = (t & 63) * 4;     // n base; wave covers 1024B contiguous
  const int boct = t >> 6;         // logical k-chunk 0..7 (= wave id)
  const float* bP = Be + (size_t)(boct * 8) * NDIM + n0 + bq;
  int bWOff[4];
#pragma unroll
  for (int c = 0; c < 4; ++c) {
    int row = bq + c;
    int fr = (row ^ (row >> 2)) & 7;
    bWOff[c] = ASZ + row * 64 + (boct ^ fr) * 8;  // u16 units; conflict-free
  }

  // ds_read addressing (32x32x16): row = base + r32, k-granule per step s:
  // logical g = 2s + hv, physical = g ^ FR, FR = (r32 ^ (r32>>2)) & 7.
  const int r32 = lane & 31, hv = lane >> 5;
  const int FR = (r32 ^ (r32 >> 2)) & 7;
  int colK[4];
#pragma unroll
  for (int s = 0; s < 4; ++s) colK[s] = (((s << 1) | hv) ^ FR) * 8;  // u16 units
  const int aBase = (wr * 128 + r32) * 64;         // A row base (m stride 2048)
  const int bBase = ASZ + (wc * 64 + r32) * 64;    // B row base (n stride 2048)

  f32x16 acc[4][2];
#pragma unroll
  for (int m = 0; m < 4; ++m)
#pragma unroll
    for (int n = 0; n < 2; ++n)
#pragma unroll
      for (int i = 0; i < 16; ++i) acc[m][n][i] = 0.f;

  f32x4 bv4[8];

  // ---- prologue: stage K-tile 0 into buffer 0 (B loads first) ----
#pragma unroll
  for (int j = 0; j < 8; ++j) bv4[j] = *(const f32x4*)(bP + (size_t)j * NDIM);
#pragma unroll
  for (int p = 0; p < 4; ++p) gl_lds16(aSrc[p], &lds[ldsOffA[p]]);
#pragma unroll
  for (int c = 0; c < 4; ++c) {
    union { u16x8 v; unsigned w[4]; } o;
#pragma unroll
    for (int j = 0; j < 4; ++j) o.w[j] = cvt_pk_bf16(bv4[2 * j][c], bv4[2 * j + 1][c]);
    *(u16x8*)(&lds[bWOff[c]]) = o.v;
  }
  S_WAIT_ALL();
  S_BAR();

  for (int kt = 0; kt < NK; ++kt) {
    const u16* sb = &lds[(kt & 1) * BUFSZ];
    u16* nb = &lds[((kt + 1) & 1) * BUFSZ];
    const bool pre = (kt + 1 < NK);
    if (pre) {
      const int ko = (kt + 1) * BK;
#pragma unroll
      for (int j = 0; j < 8; ++j)
        bv4[j] = *(const f32x4*)(bP + (size_t)(ko + j) * NDIM);
#pragma unroll
      for (int p = 0; p < 4; ++p) gl_lds16(aSrc[p] + ko, nb + ldsOffA[p]);
    }

#pragma unroll
    for (int s = 0; s < 4; ++s) {
      bf16x8 af[4], bv[2];
#pragma unroll
      for (int m = 0; m < 4; ++m)
        af[m] = *(const bf16x8*)(sb + aBase + m * 2048 + colK[s]);
#pragma unroll
      for (int n = 0; n < 2; ++n)
        bv[n] = *(const bf16x8*)(sb + bBase + n * 2048 + colK[s]);
      __builtin_amdgcn_s_setprio(1);
#pragma unroll
      for (int m = 0; m < 4; ++m)
#pragma unroll
        for (int n = 0; n < 2; ++n)
          acc[m][n] = __builtin_amdgcn_mfma_f32_32x32x16_bf16(af[m], bv[n], acc[m][n], 0, 0, 0);
      __builtin_amdgcn_s_setprio(0);
    }

    if (pre) {
#pragma unroll
      for (int c = 0; c < 4; ++c) {
        union { u16x8 v; unsigned w[4]; } o;
#pragma unroll
        for (int j = 0; j < 4; ++j) o.w[j] = cvt_pk_bf16(bv4[2 * j][c], bv4[2 * j + 1][c]);
        *(u16x8*)(nb + bWOff[c]) = o.v;
      }
    }
    S_WAIT_ALL();
    S_BAR();
  }

  // ---------- epilogue (32x32 C/D: col=lane&31, row=(i&3)+8*(i>>2)+4*hv) ----------
  if (EPI == 0) {
    u16* Hrow = Hout + (size_t)ez * MDIM * NDIM;
#pragma unroll
    for (int m = 0; m < 4; ++m) {
#pragma unroll
      for (int n = 0; n < 2; ++n) {
#pragma unroll
        for (int i = 0; i < 16; ++i) {
          int row = m0 + wr * 128 + m * 32 + (i & 3) + 8 * (i >> 2) + 4 * hv;
          int col = n0 + wc * 64 + n * 32 + r32;
          Hrow[(size_t)row * NDIM + col] = f2bf(gelu_tanh(acc[m][n][i]));
        }
      }
    }
  } else {
#pragma unroll
    for (int m = 0; m < 4; ++m) {
#pragma unroll
      for (int n = 0; n < 2; ++n) {
#pragma unroll
        for (int i = 0; i < 16; ++i) {
          int slot_in_e = m0 + wr * 128 + m * 32 + (i & 3) + 8 * (i >> 2) + 4 * hv;
          int gslot = e * CAP + slot_in_e;
          int s = tok_of_slot[gslot];
          if (s >= 0) {
            float g = gate_of_slot[gslot];
            int col = n0 + wc * 64 + n * 32 + r32;
            Fout[(size_t)s * NDIM + col] = g * acc[m][n][i];
          }
        }
      }
    }
  }
}

extern "C" void kernel_launch(void* const* d_in, const int* in_sizes, int n_in,
                              void* d_out, int out_size, void* d_ws, size_t ws_size,
                              hipStream_t stream) {
  (void)in_sizes; (void)n_in;
  const float* x  = (const float*)d_in[0];
  const float* wg = (const float*)d_in[1];
  const float* w1 = (const float*)d_in[2];
  const float* w2 = (const float*)d_in[3];
  float* out = (float*)d_out;

  char* ws = (char*)d_ws;
  size_t off = 0;
  auto alloc = [&](size_t b) {
    off = (off + 255) & ~(size_t)255;
    char* p = ws + off;
    off += b;
    return p;
  };
  int*   tok_expert   = (int*)alloc((size_t)S_TOK * 4);
  float* tok_gate     = (float*)alloc((size_t)S_TOK * 4);
  int*   tok_of_slot  = (int*)alloc((size_t)NE * CAP * 4);
  float* gate_of_slot = (float*)alloc((size_t)NE * CAP * 4);
  u16*   Xd           = (u16*)alloc((size_t)NE * CAP * DDIM * 2);
  size_t off_common = off;

  const size_t H_big = (size_t)NE * CAP * FDIM * 2;   // 134 MB
  const size_t H_sm  = (size_t)CAP * FDIM * 2;        // 16.8 MB
  bool big = ws_size >= off_common + H_big + 1024;

  fill_zero_kernel<<<2048, 256, 0, stream>>>((float4*)out, out_size / 4);
  gating_kernel<<<S_TOK / 4, 256, 0, stream>>>(x, wg, tok_expert, tok_gate);
  init_slots<<<(NE * CAP) / 256, 256, 0, stream>>>(tok_of_slot, gate_of_slot);
  scan_kernel<<<1, 1024, 0, stream>>>(tok_expert, tok_gate, tok_of_slot, gate_of_slot);
  scatter_kernel<<<NE * CAP, 256, 0, stream>>>(tok_of_slot, x, Xd);

  if (big) {
    u16* H = (u16*)alloc(H_big);
    moe_gemm<DDIM, FDIM, 0, NE><<<dim3(NE * 4 * (FDIM / 256)), 512, 0, stream>>>(
        Xd, w1, H, nullptr, tok_of_slot, gate_of_slot, 0);
    moe_gemm<FDIM, DDIM, 1, NE><<<dim3(NE * 4 * (DDIM / 256)), 512, 0, stream>>>(
        H, w2, nullptr, out, tok_of_slot, gate_of_slot, 0);
  } else {
    u16* H = (u16*)alloc(H_sm);
    for (int e = 0; e < NE; ++e) {
      moe_gemm<DDIM, FDIM, 0, 1><<<dim3(4 * (FDIM / 256)), 512, 0, stream>>>(
          Xd + (size_t)e * CAP * DDIM, w1 + (size_t)e * DDIM * FDIM, H, nullptr,
          tok_of_slot, gate_of_slot, e);
      moe_gemm<FDIM, DDIM, 1, 1><<<dim3(4 * (DDIM / 256)), 512, 0, stream>>>(
          H, w2 + (size_t)e * FDIM * DDIM, nullptr, out,
          tok_of_slot, gate_of_slot, e);
    }
  }
}

// Round 13
// 714.104 us; speedup vs baseline: 1.7756x; 1.0793x over previous
//
#include <hip/hip_runtime.h>

using u16 = unsigned short;
typedef __attribute__((ext_vector_type(4))) float f32x4;
typedef __attribute__((ext_vector_type(8))) short bf16x8;
typedef unsigned short u16x8 __attribute__((ext_vector_type(8)));

static constexpr int S_TOK = 8192;   // B*T
static constexpr int NE    = 8;      // experts
static constexpr int CAP   = 1024;   // capacity = S/E
static constexpr int DDIM  = 2048;   // model dim
static constexpr int FDIM  = 8192;   // ffn dim

#define S_WAIT_ALL() asm volatile("s_waitcnt vmcnt(0) lgkmcnt(0)" ::: "memory")
#define S_BAR()                                  \
  do {                                           \
    __builtin_amdgcn_sched_barrier(0);           \
    __builtin_amdgcn_s_barrier();                \
    __builtin_amdgcn_sched_barrier(0);           \
  } while (0)

__device__ __forceinline__ u16 f2bf(float f) {
  union { float fv; unsigned uv; } v; v.fv = f;
  unsigned r = v.uv + 0x7fffu + ((v.uv >> 16) & 1u);
  return (u16)(r >> 16);
}

__device__ __forceinline__ unsigned cvt_pk_bf16(float lo, float hi) {
  unsigned r;
  asm("v_cvt_pk_bf16_f32 %0, %1, %2" : "=v"(r) : "v"(lo), "v"(hi));
  return r;  // RNE, identical to f2bf
}

__device__ __forceinline__ float gelu_tanh(float x) {
  float u = 0.7978845608028654f * (x + 0.044715f * x * x * x);
  float t = 1.0f - 2.0f / (__expf(2.0f * u) + 1.0f);
  return 0.5f * x * (1.0f + t);
}

__device__ __forceinline__ void gl_lds16(const void* g, void* l) {
  __builtin_amdgcn_global_load_lds(
      (const __attribute__((address_space(1))) unsigned int*)g,
      (__attribute__((address_space(3))) unsigned int*)l, 16, 0, 0);
}

// ---------------- fast zero fill ----------------
__global__ __launch_bounds__(256) void fill_zero_kernel(float4* __restrict__ p, int n4) {
  int i = blockIdx.x * 256 + threadIdx.x;
  int stride = gridDim.x * 256;
  float4 z = {0.f, 0.f, 0.f, 0.f};
  for (; i < n4; i += stride) p[i] = z;
}

// ---------------- gating: logits fp32, softmax, argmax ----------------
__global__ __launch_bounds__(256) void gating_kernel(
    const float* __restrict__ x, const float* __restrict__ wg,
    int* __restrict__ tok_expert, float* __restrict__ tok_gate) {
  int s = blockIdx.x * 4 + (threadIdx.x >> 6);
  int lane = threadIdx.x & 63;
  const float4* xv = (const float4*)(x + (size_t)s * DDIM + lane * 32);
  float acc[8];
#pragma unroll
  for (int e = 0; e < 8; ++e) acc[e] = 0.f;
#pragma unroll
  for (int j = 0; j < 8; ++j) {
    float4 xx = xv[j];
#pragma unroll
    for (int c = 0; c < 4; ++c) {
      int i = lane * 32 + j * 4 + c;
      const float4* wrow = (const float4*)(wg + (size_t)i * 8);
      float4 w0 = wrow[0], w1 = wrow[1];
      float xe = (c == 0) ? xx.x : (c == 1) ? xx.y : (c == 2) ? xx.z : xx.w;
      acc[0] += xe * w0.x; acc[1] += xe * w0.y; acc[2] += xe * w0.z; acc[3] += xe * w0.w;
      acc[4] += xe * w1.x; acc[5] += xe * w1.y; acc[6] += xe * w1.z; acc[7] += xe * w1.w;
    }
  }
#pragma unroll
  for (int off = 32; off > 0; off >>= 1)
#pragma unroll
    for (int e = 0; e < 8; ++e) acc[e] += __shfl_xor(acc[e], off, 64);
  if (lane == 0) {
    float m = acc[0]; int ai = 0;
#pragma unroll
    for (int e = 1; e < 8; ++e) if (acc[e] > m) { m = acc[e]; ai = e; }
    float sum = 0.f;
#pragma unroll
    for (int e = 0; e < 8; ++e) sum += expf(acc[e] - m);
    tok_expert[s] = ai;
    tok_gate[s] = 1.0f / sum;
  }
}

// -------- deterministic capacity assignment (cumsum over token order) --------
// Also initializes empty slots (p >= total[e]) to {-1, 0} — disjoint from the
// occupied-slot writes, so no ordering needed.
__global__ __launch_bounds__(1024) void scan_kernel(
    const int* __restrict__ tok_expert, const float* __restrict__ tok_gate,
    int* __restrict__ tok_of_slot, float* __restrict__ gate_of_slot) {
  __shared__ int cnt[1024][8];
  int t = threadIdx.x;
  int e8[8];
  int local[8];
#pragma unroll
  for (int e = 0; e < 8; ++e) local[e] = 0;
#pragma unroll
  for (int j = 0; j < 8; ++j) {
    int e = tok_expert[t * 8 + j];
    e8[j] = e;
    local[e]++;
  }
#pragma unroll
  for (int e = 0; e < 8; ++e) cnt[t][e] = local[e];
  __syncthreads();
  for (int off = 1; off < 1024; off <<= 1) {
    int v[8];
    bool has = (t >= off);
    if (has) {
#pragma unroll
      for (int e = 0; e < 8; ++e) v[e] = cnt[t - off][e];
    }
    __syncthreads();
    if (has) {
#pragma unroll
      for (int e = 0; e < 8; ++e) cnt[t][e] += v[e];
    }
    __syncthreads();
  }
  int base[8];
#pragma unroll
  for (int e = 0; e < 8; ++e) base[e] = (t == 0) ? 0 : cnt[t - 1][e];
#pragma unroll
  for (int j = 0; j < 8; ++j) {
    int s = t * 8 + j;
    int e = e8[j];
    int p = base[e]++;
    if (p < CAP) {
      tok_of_slot[e * CAP + p] = s;
      gate_of_slot[e * CAP + p] = tok_gate[s];
    }
  }
  // init empty slots: thread t owns slot p=t of every expert
#pragma unroll
  for (int e = 0; e < 8; ++e) {
    int total = cnt[1023][e];
    if (t >= total) {
      tok_of_slot[e * CAP + t] = -1;
      gate_of_slot[e * CAP + t] = 0.f;
    }
  }
}

// ---- dispatch: gather x rows -> bf16 Xd [E][CAP][D]; empty slots -> zeros ----
__global__ __launch_bounds__(256) void scatter_kernel(
    const int* __restrict__ tok_of_slot, const float* __restrict__ x,
    u16* __restrict__ Xd) {
  int slot = blockIdx.x;
  int s = tok_of_slot[slot];
  int t = threadIdx.x;
  u16x8 v;
  if (s >= 0) {
    const float4* xr = (const float4*)(x + (size_t)s * DDIM + t * 8);
    float4 a = xr[0], b = xr[1];
    v[0] = f2bf(a.x); v[1] = f2bf(a.y); v[2] = f2bf(a.z); v[3] = f2bf(a.w);
    v[4] = f2bf(b.x); v[5] = f2bf(b.y); v[6] = f2bf(b.z); v[7] = f2bf(b.w);
  } else {
#pragma unroll
    for (int j = 0; j < 8; ++j) v[j] = 0;
  }
  *(u16x8*)(Xd + (size_t)slot * DDIM + t * 8) = v;
}

// ---- pipelined bf16 GEMM with fused fp32->bf16 weight staging (R9, verified) ----
// C[1024xN] = A[1024xK](bf16) * W[KxN](fp32, row-major).
// BM=BN=256, BK=64, 512 thr / 8 waves (2M x 4N), wave-tile 128x64.
// LDS layout swizzle F(row) = (row ^ (row>>2)) & 7 : ds_read_b128 AND the B
// ds_write_b128 both bank-conflict-free; B global loads wave-contiguous 1024B.
// One vmcnt(0)+lgkmcnt(0)+barrier per K-tile; prefetch issued right after the
// barrier, the 64-MFMA body covers the latency, cvt+ds_write land at body end.
// EPI=0: gelu -> bf16 H ; EPI=1: gated scatter to fp32 out.
template <int KDIM, int NDIM, int EPI, int NEXP>
__global__ __launch_bounds__(512, 2) void moe_gemm(
    const u16* __restrict__ A, const float* __restrict__ Bf,
    u16* __restrict__ Hout, float* __restrict__ Fout,
    const int* __restrict__ tok_of_slot, const float* __restrict__ gate_of_slot,
    int e_base) {
  constexpr int MDIM = 1024;
  constexpr int BM = 256, BN = 256, BK = 64;
  constexpr int MT = MDIM / BM;              // 4
  constexpr int NK = KDIM / BK;
  constexpr int ASZ = BM * BK;               // 16384 u16 (32 KB)
  constexpr int BSZ = BN * BK;               // 16384 u16 (32 KB)
  constexpr int BUFSZ = ASZ + BSZ;
  __shared__ u16 lds[2 * BUFSZ];             // 128 KB

  const int t = threadIdx.x;
  const int lane = t & 63, wave = t >> 6;
  const int wr = wave >> 2, wc = wave & 3;   // 2 x 4

  int id = blockIdx.x;
  int ez = id & (NEXP - 1);
  int w = id / NEXP;
  int mt = w & (MT - 1);
  int nt = w / MT;
  int m0 = mt * BM, n0 = nt * BN;
  int e = e_base + ez;

  const u16* Ae = A + (size_t)ez * MDIM * KDIM;
  const float* Be = Bf + (size_t)ez * (size_t)KDIM * NDIM;

  // A staging (global_load_lds, source pre-swizzled by F(row))
  const u16* aSrc[4];
  int ldsOffA[4];
#pragma unroll
  for (int p = 0; p < 4; ++p) {
    int c = t + p * 512;
    int row = c >> 3;
    int fr = (row ^ (row >> 2)) & 7;
    int j = (c & 7) ^ fr;
    aSrc[p] = Ae + (size_t)(m0 + row) * KDIM + j * 8;
    ldsOffA[p] = c * 8;
  }

  // B reg staging: bq = lane-contiguous n, boct = wave's k-oct
  const int bq = (t & 63) * 4;     // n base; wave covers 1024B contiguous
  const int boct = t >> 6;         // logical k-chunk 0..7 (= wave id)
  const float* bP = Be + (size_t)(boct * 8) * NDIM + n0 + bq;
  int bWOff[4];
#pragma unroll
  for (int c = 0; c < 4; ++c) {
    int row = bq + c;
    int fr = (row ^ (row >> 2)) & 7;
    bWOff[c] = ASZ + row * 64 + (boct ^ fr) * 8;  // u16 units; conflict-free
  }

  // ds_read addressing: col = (K ^ 4*((kk^frag)&1)) * 8, K = h ^ (r&7) ^ (r>>2)
  const int r = lane & 15, h = lane >> 4;
  const int Kk = h ^ (r & 7) ^ (r >> 2);
  const int pE = Kk * 8;            // (kk ^ frag) even
  const int pO = (Kk ^ 4) * 8;      // (kk ^ frag) odd
  const int aBase = (wr * 128 + r) * 64;         // A row base
  const int bBase = ASZ + (wc * 64 + r) * 64;    // B row base

  f32x4 acc[8][4];
#pragma unroll
  for (int m = 0; m < 8; ++m)
#pragma unroll
    for (int n = 0; n < 4; ++n) acc[m][n] = f32x4{0.f, 0.f, 0.f, 0.f};

  f32x4 bv4[8];

  // ---- prologue: stage K-tile 0 into buffer 0 ----
#pragma unroll
  for (int j = 0; j < 8; ++j) bv4[j] = *(const f32x4*)(bP + (size_t)j * NDIM);
#pragma unroll
  for (int p = 0; p < 4; ++p) gl_lds16(aSrc[p], &lds[ldsOffA[p]]);
#pragma unroll
  for (int c = 0; c < 4; ++c) {
    union { u16x8 v; unsigned w[4]; } o;
#pragma unroll
    for (int j = 0; j < 4; ++j) o.w[j] = cvt_pk_bf16(bv4[2 * j][c], bv4[2 * j + 1][c]);
    *(u16x8*)(&lds[bWOff[c]]) = o.v;
  }
  S_WAIT_ALL();
  S_BAR();

  for (int kt = 0; kt < NK; ++kt) {
    const u16* sb = &lds[(kt & 1) * BUFSZ];
    u16* nb = &lds[((kt + 1) & 1) * BUFSZ];
    const bool pre = (kt + 1 < NK);
    if (pre) {
      const int ko = (kt + 1) * BK;
#pragma unroll
      for (int p = 0; p < 4; ++p) gl_lds16(aSrc[p] + ko, nb + ldsOffA[p]);
#pragma unroll
      for (int j = 0; j < 8; ++j)
        bv4[j] = *(const f32x4*)(bP + (size_t)(ko + j) * NDIM);
    }

#pragma unroll
    for (int kk = 0; kk < 2; ++kk) {
      bf16x8 af[8], bv[4];
#pragma unroll
      for (int m = 0; m < 8; ++m)
        af[m] = *(const bf16x8*)(sb + aBase + m * 1024 + (((kk ^ m) & 1) ? pO : pE));
#pragma unroll
      for (int n = 0; n < 4; ++n)
        bv[n] = *(const bf16x8*)(sb + bBase + n * 1024 + (((kk ^ n) & 1) ? pO : pE));
      __builtin_amdgcn_s_setprio(1);
#pragma unroll
      for (int m = 0; m < 8; ++m)
#pragma unroll
        for (int n = 0; n < 4; ++n)
          acc[m][n] = __builtin_amdgcn_mfma_f32_16x16x32_bf16(af[m], bv[n], acc[m][n], 0, 0, 0);
      __builtin_amdgcn_s_setprio(0);
    }

    if (pre) {
#pragma unroll
      for (int c = 0; c < 4; ++c) {
        union { u16x8 v; unsigned w[4]; } o;
#pragma unroll
        for (int j = 0; j < 4; ++j) o.w[j] = cvt_pk_bf16(bv4[2 * j][c], bv4[2 * j + 1][c]);
        *(u16x8*)(nb + bWOff[c]) = o.v;
      }
    }
    S_WAIT_ALL();
    S_BAR();
  }

  // ---------- epilogue ----------
  if (EPI == 0) {
    u16* Hrow = Hout + (size_t)ez * MDIM * NDIM;
#pragma unroll
    for (int m = 0; m < 8; ++m) {
#pragma unroll
      for (int rr = 0; rr < 4; ++rr) {
        int row = m0 + wr * 128 + m * 16 + h * 4 + rr;
#pragma unroll
        for (int n = 0; n < 4; ++n) {
          int col = n0 + wc * 64 + n * 16 + r;
          Hrow[(size_t)row * NDIM + col] = f2bf(gelu_tanh(acc[m][n][rr]));
        }
      }
    }
  } else {
#pragma unroll
    for (int m = 0; m < 8; ++m) {
#pragma unroll
      for (int rr = 0; rr < 4; ++rr) {
        int slot_in_e = m0 + wr * 128 + m * 16 + h * 4 + rr;
        int gslot = e * CAP + slot_in_e;
        int s = tok_of_slot[gslot];
        if (s >= 0) {
          float g = gate_of_slot[gslot];
#pragma unroll
          for (int n = 0; n < 4; ++n) {
            int col = n0 + wc * 64 + n * 16 + r;
            Fout[(size_t)s * NDIM + col] = g * acc[m][n][rr];
          }
        }
      }
    }
  }
}

extern "C" void kernel_launch(void* const* d_in, const int* in_sizes, int n_in,
                              void* d_out, int out_size, void* d_ws, size_t ws_size,
                              hipStream_t stream) {
  (void)in_sizes; (void)n_in;
  const float* x  = (const float*)d_in[0];
  const float* wg = (const float*)d_in[1];
  const float* w1 = (const float*)d_in[2];
  const float* w2 = (const float*)d_in[3];
  float* out = (float*)d_out;

  char* ws = (char*)d_ws;
  size_t off = 0;
  auto alloc = [&](size_t b) {
    off = (off + 255) & ~(size_t)255;
    char* p = ws + off;
    off += b;
    return p;
  };
  int*   tok_expert   = (int*)alloc((size_t)S_TOK * 4);
  float* tok_gate     = (float*)alloc((size_t)S_TOK * 4);
  int*   tok_of_slot  = (int*)alloc((size_t)NE * CAP * 4);
  float* gate_of_slot = (float*)alloc((size_t)NE * CAP * 4);
  u16*   Xd           = (u16*)alloc((size_t)NE * CAP * DDIM * 2);
  size_t off_common = off;

  const size_t H_big = (size_t)NE * CAP * FDIM * 2;   // 134 MB
  const size_t H_sm  = (size_t)CAP * FDIM * 2;        // 16.8 MB
  bool big = ws_size >= off_common + H_big + 1024;

  fill_zero_kernel<<<2048, 256, 0, stream>>>((float4*)out, out_size / 4);
  gating_kernel<<<S_TOK / 4, 256, 0, stream>>>(x, wg, tok_expert, tok_gate);
  scan_kernel<<<1, 1024, 0, stream>>>(tok_expert, tok_gate, tok_of_slot, gate_of_slot);
  scatter_kernel<<<NE * CAP, 256, 0, stream>>>(tok_of_slot, x, Xd);

  if (big) {
    u16* H = (u16*)alloc(H_big);
    moe_gemm<DDIM, FDIM, 0, NE><<<dim3(NE * 4 * (FDIM / 256)), 512, 0, stream>>>(
        Xd, w1, H, nullptr, tok_of_slot, gate_of_slot, 0);
    moe_gemm<FDIM, DDIM, 1, NE><<<dim3(NE * 4 * (DDIM / 256)), 512, 0, stream>>>(
        H, w2, nullptr, out, tok_of_slot, gate_of_slot, 0);
  } else {
    u16* H = (u16*)alloc(H_sm);
    for (int e = 0; e < NE; ++e) {
      moe_gemm<DDIM, FDIM, 0, 1><<<dim3(4 * (FDIM / 256)), 512, 0, stream>>>(
          Xd + (size_t)e * CAP * DDIM, w1 + (size_t)e * DDIM * FDIM, H, nullptr,
          tok_of_slot, gate_of_slot, e);
      moe_gemm<FDIM, DDIM, 1, 1><<<dim3(4 * (DDIM / 256)), 512, 0, stream>>>(
          H, w2 + (size_t)e * FDIM * DDIM, nullptr, out,
          tok_of_slot, gate_of_slot, e);
    }
  }
}